// Round 18
// baseline (253.322 us; speedup 1.0000x reference)
//
#include <hip/hip_runtime.h>

#define DIM 1024
#define SEQ 2048

typedef unsigned short ushort_t;
typedef unsigned int u32;
typedef __attribute__((ext_vector_type(8))) short short8;
typedef __attribute__((ext_vector_type(8))) unsigned short ushort8;
typedef __attribute__((ext_vector_type(4))) float f32x4;
typedef __attribute__((ext_vector_type(16))) float f32x16;

__device__ __forceinline__ ushort_t f2bf(float x) {
    u32 u = __float_as_uint(x);
    u32 r = (u + 0x7fffu + ((u >> 16) & 1u)) >> 16;
    return (ushort_t)r;
}

__device__ __forceinline__ u32 cvtpk(float lo, float hi) {
    u32 r;
    asm("v_cvt_pk_bf16_f32 %0, %1, %2" : "=v"(r) : "v"(lo), "v"(hi));
    return r;
}

__device__ __forceinline__ void gload16(const void* g, void* l) {
    __builtin_amdgcn_global_load_lds(
        (const __attribute__((address_space(1))) u32*)g,
        (__attribute__((address_space(3))) u32*)l, 16, 0, 0);
}

// XOR-swizzled element index within a [rows][64-bf16] tile (8-elem groups)
__device__ __forceinline__ int swz8(int row, int col) {
    return row * 64 + ((((col >> 3) ^ (row & 7)) << 3) | (col & 7));
}

// ---------------------------------------------------------------------------
// fused fp32 -> bf16 conversion of all three inputs (one dispatch)
// seg0: x (1048576 x8), seg1: w_qkv (393216 x8), seg2: w_out (131072 x8)
// ---------------------------------------------------------------------------
__global__ __launch_bounds__(256) void cvt_all(const float* __restrict__ x,
                                               const float* __restrict__ wq,
                                               const float* __restrict__ wo,
                                               ushort_t* __restrict__ xb,
                                               ushort_t* __restrict__ wqb,
                                               ushort_t* __restrict__ wob) {
    for (int i = blockIdx.x * blockDim.x + threadIdx.x; i < 1572864;
         i += gridDim.x * blockDim.x) {
        const float* in; ushort_t* out; int off;
        if (i < 1048576)      { in = x;  out = xb;  off = i; }
        else if (i < 1441792) { in = wq; out = wqb; off = i - 1048576; }
        else                  { in = wo; out = wob; off = i - 1441792; }
        const float4 a = ((const float4*)in)[2 * off];
        const float4 b = ((const float4*)in)[2 * off + 1];
        ushort8 o;
        o[0] = f2bf(a.x); o[1] = f2bf(a.y); o[2] = f2bf(a.z); o[3] = f2bf(a.w);
        o[4] = f2bf(b.x); o[5] = f2bf(b.y); o[6] = f2bf(b.z); o[7] = f2bf(b.w);
        ((ushort8*)out)[off] = o;
    }
}

// ---------------------------------------------------------------------------
// bf16 GEMM, m97 structure, 128x128 tile (round-16 proven form) +
// launch_bounds(256,5): VGPR cap 102 -> 5 blocks/CU (1536/1280 = 1.2 gens).
// EPI 0 adds bijective XCD swizzle (grid 24x64, 1536%8==0): XCD x owns
// m-panels [8x,8x+8) -> A slice 2 MB L2-resident.
// EPI 0: Q (pre-scaled 0.125*log2e) and K -> [2][bh][s][64];
//        V -> TRANSPOSED buffer [bh][d=64][s=2048] (uint2-packed stores)
// EPI 1: fp32 out + bias
// ---------------------------------------------------------------------------
template <int EPI>
__global__ __launch_bounds__(256, 5) void gemm_bt(const ushort_t* __restrict__ A,
                                                  const ushort_t* __restrict__ B,
                                                  const float* __restrict__ bias,
                                                  ushort_t* __restrict__ outb,
                                                  ushort_t* __restrict__ voutb,
                                                  float* __restrict__ outf) {
    __shared__ __align__(16) ushort_t As[128 * 64];
    __shared__ __align__(16) ushort_t Bs[128 * 64];
    const int t = threadIdx.x;

    int bx = blockIdx.x, by = blockIdx.y;
    if (EPI == 0) {
        // bijective XCD swizzle: grid (24,64), nwg=1536, 192 blocks/XCD
        const int bid = bx + by * 24;
        const int swzb = (bid & 7) * 192 + (bid >> 3);
        bx = swzb % 24;
        by = swzb / 24;
    }
    const int m0 = by * 128, n0 = bx * 128;

    const int w = t >> 6, lane = t & 63, k15 = lane & 15, g = lane >> 4;
    const int wm = (w >> 1) * 64, wn = (w & 1) * 64;
    const int srow = t >> 3, scol = (t & 7) * 8;

    f32x4 acc[4][4] = {};

    for (int k0 = 0; k0 < 1024; k0 += 64) {
        __syncthreads();
        #pragma unroll
        for (int i = 0; i < 4; ++i) {
            gload16(&A[(size_t)(m0 + i * 32 + srow) * 1024 + k0 + scol],
                    ((char*)As) + i * 4096 + t * 16);
            gload16(&B[(size_t)(n0 + i * 32 + srow) * 1024 + k0 + scol],
                    ((char*)Bs) + i * 4096 + t * 16);
        }
        __syncthreads();
        #pragma unroll
        for (int ks = 0; ks < 2; ++ks) {
            short8 af[4], bf[4];
            #pragma unroll
            for (int i = 0; i < 4; ++i) {
                af[i] = *(const short8*)&As[(wm + i * 16 + k15) * 64 + ks * 32 + g * 8];
                bf[i] = *(const short8*)&Bs[(wn + i * 16 + k15) * 64 + ks * 32 + g * 8];
            }
            #pragma unroll
            for (int mi = 0; mi < 4; ++mi)
                #pragma unroll
                for (int ni = 0; ni < 4; ++ni)
                    acc[mi][ni] = __builtin_amdgcn_mfma_f32_16x16x32_bf16(
                        af[mi], bf[ni], acc[mi][ni], 0, 0, 0);
        }
    }

    if (EPI == 0) {
        #pragma unroll
        for (int mi = 0; mi < 4; ++mi) {
            const int mbase = m0 + wm + mi * 16 + g * 4;
            const int b = mbase >> 11, s0 = mbase & 2047;
            #pragma unroll
            for (int ni = 0; ni < 4; ++ni) {
                const int e = n0 + wn + ni * 16 + k15;
                const int qi = e >> 10, h = (e >> 6) & 15, hd = e & 63;
                const int bh = b * 16 + h;
                if (qi == 2) {
                    // V transposed: [bh][d=hd][s], 4 consecutive s packed
                    const u32 lo = cvtpk(acc[mi][ni][0], acc[mi][ni][1]);
                    const u32 hi = cvtpk(acc[mi][ni][2], acc[mi][ni][3]);
                    *(uint2*)&voutb[((size_t)bh * 64 + hd) * SEQ + s0] = make_uint2(lo, hi);
                } else {
                    // fold softmax scale * log2(e) into Q (exp2-direct softmax)
                    const float scl = (qi == 0) ? 0.180336880f : 1.0f;
                    #pragma unroll
                    for (int r = 0; r < 4; ++r)
                        outb[((size_t)(qi * 64 + bh) * SEQ + s0 + r) * 64 + hd] =
                            f2bf(acc[mi][ni][r] * scl);
                }
            }
        }
    } else {
        #pragma unroll
        for (int mi = 0; mi < 4; ++mi) {
            #pragma unroll
            for (int r = 0; r < 4; ++r) {
                const size_t m = m0 + wm + mi * 16 + g * 4 + r;
                #pragma unroll
                for (int ni = 0; ni < 4; ++ni) {
                    const int e = n0 + wn + ni * 16 + k15;
                    outf[m * 1024 + e] = acc[mi][ni][r] + bias[e];
                }
            }
        }
    }
}

// ---------------------------------------------------------------------------
// Flash attention, 32x32x16 bf16 MFMA, swapped operands, DQ=2 (exact round-16
// form, proven): each wave owns TWO 32-row q-sets, 2 MFMAs per kf/vf read.
// NO-MAX-SUB softmax (exp2-direct). P in registers via cvt_pk+permlane32_swap.
// 2-phase double-buffered gload_lds staging. XCD-aware remap.
// ---------------------------------------------------------------------------
__global__ __launch_bounds__(256, 2) void attn_mfma(const ushort_t* __restrict__ qk,
                                                    const ushort_t* __restrict__ vt,
                                                    ushort_t* __restrict__ aout) {
    __shared__ __align__(16) ushort_t Ks[2][64 * 64];
    __shared__ __align__(16) ushort_t Vs[2][64 * 64];   // V^T tiles: [d][key]

    const int t = threadIdx.x, w = t >> 6, lane = t & 63;
    const int l31 = lane & 31, hi = lane >> 5;

    const int bid = blockIdx.x;
    const int j   = bid >> 3;
    const int bh  = ((bid & 7) << 3) + (j >> 3);
    const int q0  = (j & 7) * 256;

    const ushort_t* Qp = qk + (size_t)bh * SEQ * 64;
    const ushort_t* Kp = qk + (size_t)(64 + bh) * SEQ * 64;
    const ushort_t* Vp = vt + (size_t)bh * 64 * SEQ;    // [d][s]
    const int wqA = q0 + w * 64 + l31;
    const int wqB = wqA + 32;

    const int srow = t >> 3;
    const int scb8 = ((t & 7) ^ (srow & 7)) * 8;

    const ushort_t* kpA = Kp + (size_t)srow * 64 + scb8;
    const ushort_t* vpA = Vp + (size_t)srow * SEQ + scb8;

    short8 qfA[4], qfB[4];
    #pragma unroll
    for (int kc = 0; kc < 4; ++kc) {
        qfA[kc] = *(const short8*)&Qp[(size_t)wqA * 64 + kc * 16 + hi * 8];
        qfB[kc] = *(const short8*)&Qp[(size_t)wqB * 64 + kc * 16 + hi * 8];
    }

    gload16(kpA,            ((char*)Ks) + t * 16);
    gload16(kpA + 32 * 64,  ((char*)Ks) + 4096 + t * 16);
    gload16(vpA,            ((char*)Vs) + t * 16);
    gload16(vpA + 32 * SEQ, ((char*)Vs) + 4096 + t * 16);
    kpA += 64 * 64; vpA += 64;
    __syncthreads();

    f32x16 oA[2] = {}, oB[2] = {};
    float liA = 0.f, liB = 0.f;
    int cur = 0;

    for (int kt = 0; kt < SEQ / 64; ++kt) {
        if (kt + 1 < SEQ / 64) {
            char* dstK = ((char*)Ks) + (cur ^ 1) * 8192 + t * 16;
            char* dstV = ((char*)Vs) + (cur ^ 1) * 8192 + t * 16;
            gload16(kpA,            dstK);
            gload16(kpA + 32 * 64,  dstK + 4096);
            gload16(vpA,            dstV);
            gload16(vpA + 32 * SEQ, dstV + 4096);
            kpA += 64 * 64; vpA += 64;
        }

        f32x16 sA[2] = {}, sB[2] = {};
        __builtin_amdgcn_s_setprio(1);
        #pragma unroll
        for (int kt2 = 0; kt2 < 2; ++kt2) {
            #pragma unroll
            for (int kc = 0; kc < 4; ++kc) {
                const short8 kf = *(const short8*)&Ks[cur][swz8(kt2 * 32 + l31, kc * 16 + hi * 8)];
                sA[kt2] = __builtin_amdgcn_mfma_f32_32x32x16_bf16(kf, qfA[kc], sA[kt2], 0, 0, 0);
                sB[kt2] = __builtin_amdgcn_mfma_f32_32x32x16_bf16(kf, qfB[kc], sB[kt2], 0, 0, 0);
            }
        }
        __builtin_amdgcn_s_setprio(0);

        uint4 pbA[4], pbB[4];
        {
            float t0 = 0.f, t1 = 0.f, t2 = 0.f, t3 = 0.f;
            #pragma unroll
            for (int kt2 = 0; kt2 < 2; ++kt2)
                #pragma unroll
                for (int r = 0; r < 16; r += 4) {
                    const float e0 = __builtin_amdgcn_exp2f(sA[kt2][r + 0]);
                    const float e1 = __builtin_amdgcn_exp2f(sA[kt2][r + 1]);
                    const float e2 = __builtin_amdgcn_exp2f(sA[kt2][r + 2]);
                    const float e3 = __builtin_amdgcn_exp2f(sA[kt2][r + 3]);
                    sA[kt2][r + 0] = e0; sA[kt2][r + 1] = e1;
                    sA[kt2][r + 2] = e2; sA[kt2][r + 3] = e3;
                    t0 += e0; t1 += e1; t2 += e2; t3 += e3;
                }
            float rs = (t0 + t1) + (t2 + t3);
            rs += __shfl_xor(rs, 32);
            liA += rs;
            #pragma unroll
            for (int ks2 = 0; ks2 < 4; ++ks2) {
                const int r0 = (ks2 & 1) * 8;
                const int sv = ks2 >> 1;
                u32 pA = cvtpk(sA[sv][r0 + 0], sA[sv][r0 + 1]);
                u32 pB = cvtpk(sA[sv][r0 + 2], sA[sv][r0 + 3]);
                u32 pC = cvtpk(sA[sv][r0 + 4], sA[sv][r0 + 5]);
                u32 pD = cvtpk(sA[sv][r0 + 6], sA[sv][r0 + 7]);
                asm volatile("v_permlane32_swap_b32 %0, %1" : "+v"(pA), "+v"(pC));
                asm volatile("v_permlane32_swap_b32 %0, %1" : "+v"(pB), "+v"(pD));
                pbA[ks2] = make_uint4(pA, pB, pC, pD);
            }
        }
        {
            float t0 = 0.f, t1 = 0.f, t2 = 0.f, t3 = 0.f;
            #pragma unroll
            for (int kt2 = 0; kt2 < 2; ++kt2)
                #pragma unroll
                for (int r = 0; r < 16; r += 4) {
                    const float e0 = __builtin_amdgcn_exp2f(sB[kt2][r + 0]);
                    const float e1 = __builtin_amdgcn_exp2f(sB[kt2][r + 1]);
                    const float e2 = __builtin_amdgcn_exp2f(sB[kt2][r + 2]);
                    const float e3 = __builtin_amdgcn_exp2f(sB[kt2][r + 3]);
                    sB[kt2][r + 0] = e0; sB[kt2][r + 1] = e1;
                    sB[kt2][r + 2] = e2; sB[kt2][r + 3] = e3;
                    t0 += e0; t1 += e1; t2 += e2; t3 += e3;
                }
            float rs = (t0 + t1) + (t2 + t3);
            rs += __shfl_xor(rs, 32);
            liB += rs;
            #pragma unroll
            for (int ks2 = 0; ks2 < 4; ++ks2) {
                const int r0 = (ks2 & 1) * 8;
                const int sv = ks2 >> 1;
                u32 pA = cvtpk(sB[sv][r0 + 0], sB[sv][r0 + 1]);
                u32 pB = cvtpk(sB[sv][r0 + 2], sB[sv][r0 + 3]);
                u32 pC = cvtpk(sB[sv][r0 + 4], sB[sv][r0 + 5]);
                u32 pD = cvtpk(sB[sv][r0 + 6], sB[sv][r0 + 7]);
                asm volatile("v_permlane32_swap_b32 %0, %1" : "+v"(pA), "+v"(pC));
                asm volatile("v_permlane32_swap_b32 %0, %1" : "+v"(pB), "+v"(pD));
                pbB[ks2] = make_uint4(pA, pB, pC, pD);
            }
        }

        __builtin_amdgcn_s_setprio(1);
        #pragma unroll
        for (int dt = 0; dt < 2; ++dt) {
            #pragma unroll
            for (int ks2 = 0; ks2 < 4; ++ks2) {
                const short8 vf = *(const short8*)&Vs[cur][swz8(dt * 32 + l31, ks2 * 16 + hi * 8)];
                oA[dt] = __builtin_amdgcn_mfma_f32_32x32x16_bf16(
                    vf, *(const short8*)&pbA[ks2], oA[dt], 0, 0, 0);
                oB[dt] = __builtin_amdgcn_mfma_f32_32x32x16_bf16(
                    vf, *(const short8*)&pbB[ks2], oB[dt], 0, 0, 0);
            }
        }
        __builtin_amdgcn_s_setprio(0);

        __syncthreads();
        cur ^= 1;
    }

    const int b = bh >> 4, h = bh & 15;
    {
        const float inv = 1.0f / liA;
        const size_t base = ((size_t)b * SEQ + wqA) * DIM + h * 64;
        #pragma unroll
        for (int dt = 0; dt < 2; ++dt)
            #pragma unroll
            for (int rq = 0; rq < 4; ++rq) {
                const u32 lo = cvtpk(oA[dt][4 * rq + 0] * inv, oA[dt][4 * rq + 1] * inv);
                const u32 hg = cvtpk(oA[dt][4 * rq + 2] * inv, oA[dt][4 * rq + 3] * inv);
                *(uint2*)&aout[base + dt * 32 + rq * 8 + hi * 4] = make_uint2(lo, hg);
            }
    }
    {
        const float inv = 1.0f / liB;
        const size_t base = ((size_t)b * SEQ + wqB) * DIM + h * 64;
        #pragma unroll
        for (int dt = 0; dt < 2; ++dt)
            #pragma unroll
            for (int rq = 0; rq < 4; ++rq) {
                const u32 lo = cvtpk(oB[dt][4 * rq + 0] * inv, oB[dt][4 * rq + 1] * inv);
                const u32 hg = cvtpk(oB[dt][4 * rq + 2] * inv, oB[dt][4 * rq + 3] * inv);
                *(uint2*)&aout[base + dt * 32 + rq * 8 + hi * 4] = make_uint2(lo, hg);
            }
    }
}

// ---------------------------------------------------------------------------
extern "C" void kernel_launch(void* const* d_in, const int* in_sizes, int n_in,
                              void* d_out, int out_size, void* d_ws, size_t ws_size,
                              hipStream_t stream) {
    const float* x     = (const float*)d_in[0];   // [4,2048,1024]
    const float* w_qkv = (const float*)d_in[1];   // [3072,1024]
    const float* w_out = (const float*)d_in[2];   // [1024,1024]
    const float* b_out = (const float*)d_in[3];   // [1024]
    float* out = (float*)d_out;

    char* ws = (char*)d_ws;
    ushort_t* xb    = (ushort_t*)ws;                                // 16 MB
    ushort_t* wqkvb = (ushort_t*)(ws + (size_t)16 * 1024 * 1024);   // 6 MB
    ushort_t* woutb = (ushort_t*)(ws + (size_t)22 * 1024 * 1024);   // 2 MB
    ushort_t* qkb   = (ushort_t*)(ws + (size_t)24 * 1024 * 1024);   // 32 MB: [2][64][2048][64]
    ushort_t* vtb   = (ushort_t*)(ws + (size_t)56 * 1024 * 1024);   // 16 MB: [64][64][2048]
    ushort_t* aob   = (ushort_t*)(ws + (size_t)72 * 1024 * 1024);   // 16 MB: [8192][1024]

    cvt_all<<<2048, 256, 0, stream>>>(x, w_qkv, w_out, xb, wqkvb, woutb);

    gemm_bt<0><<<dim3(24, 64), 256, 0, stream>>>(xb, wqkvb, nullptr, qkb, vtb, nullptr);
    attn_mfma<<<512, 256, 0, stream>>>(qkb, vtb, aob);
    gemm_bt<1><<<dim3(8, 64), 256, 0, stream>>>(aob, woutb, b_out, nullptr, nullptr, out);
}

// Round 19
// 201.792 us; speedup vs baseline: 1.2554x; 1.2554x over previous
//
#include <hip/hip_runtime.h>

#define DIM 1024
#define SEQ 2048

typedef unsigned short ushort_t;
typedef unsigned int u32;
typedef __attribute__((ext_vector_type(8))) short short8;
typedef __attribute__((ext_vector_type(8))) unsigned short ushort8;
typedef __attribute__((ext_vector_type(4))) float f32x4;
typedef __attribute__((ext_vector_type(16))) float f32x16;

__device__ __forceinline__ ushort_t f2bf(float x) {
    u32 u = __float_as_uint(x);
    u32 r = (u + 0x7fffu + ((u >> 16) & 1u)) >> 16;
    return (ushort_t)r;
}

__device__ __forceinline__ u32 cvtpk(float lo, float hi) {
    u32 r;
    asm("v_cvt_pk_bf16_f32 %0, %1, %2" : "=v"(r) : "v"(lo), "v"(hi));
    return r;
}

__device__ __forceinline__ void gload16(const void* g, void* l) {
    __builtin_amdgcn_global_load_lds(
        (const __attribute__((address_space(1))) u32*)g,
        (__attribute__((address_space(3))) u32*)l, 16, 0, 0);
}

// XOR-swizzled element index within a [rows][64-bf16] tile (8-elem groups)
__device__ __forceinline__ int swz8(int row, int col) {
    return row * 64 + ((((col >> 3) ^ (row & 7)) << 3) | (col & 7));
}

// ---------------------------------------------------------------------------
// fused fp32 -> bf16 conversion of all three inputs (one dispatch)
// ---------------------------------------------------------------------------
__global__ __launch_bounds__(256) void cvt_all(const float* __restrict__ x,
                                               const float* __restrict__ wq,
                                               const float* __restrict__ wo,
                                               ushort_t* __restrict__ xb,
                                               ushort_t* __restrict__ wqb,
                                               ushort_t* __restrict__ wob) {
    for (int i = blockIdx.x * blockDim.x + threadIdx.x; i < 1572864;
         i += gridDim.x * blockDim.x) {
        const float* in; ushort_t* out; int off;
        if (i < 1048576)      { in = x;  out = xb;  off = i; }
        else if (i < 1441792) { in = wq; out = wqb; off = i - 1048576; }
        else                  { in = wo; out = wob; off = i - 1441792; }
        const float4 a = ((const float4*)in)[2 * off];
        const float4 b = ((const float4*)in)[2 * off + 1];
        ushort8 o;
        o[0] = f2bf(a.x); o[1] = f2bf(a.y); o[2] = f2bf(a.z); o[3] = f2bf(a.w);
        o[4] = f2bf(b.x); o[5] = f2bf(b.y); o[6] = f2bf(b.z); o[7] = f2bf(b.w);
        ((ushort8*)out)[off] = o;
    }
}

// ---------------------------------------------------------------------------
// bf16 GEMM, m97 structure, 128x128 tile — EXACT round-16 resource shape
// (no min-waves launch bound: r18 proved a cap below the ~104-VGPR live
// range forces catastrophic spill, WRITE_SIZE 49->166 MB).
// EPI 0 adds ONLY a bijective XCD swizzle (SALU index remap, zero resource
// cost): XCD x owns m-panels [8x,8x+8) -> A slice 2 MB L2-resident.
// EPI 0: Q (pre-scaled 0.125*log2e) and K -> [2][bh][s][64];
//        V -> TRANSPOSED buffer [bh][d=64][s=2048] (uint2-packed stores)
// EPI 1: fp32 out + bias
// ---------------------------------------------------------------------------
template <int EPI>
__global__ __launch_bounds__(256) void gemm_bt(const ushort_t* __restrict__ A,
                                               const ushort_t* __restrict__ B,
                                               const float* __restrict__ bias,
                                               ushort_t* __restrict__ outb,
                                               ushort_t* __restrict__ voutb,
                                               float* __restrict__ outf) {
    __shared__ __align__(16) ushort_t As[128 * 64];
    __shared__ __align__(16) ushort_t Bs[128 * 64];
    const int t = threadIdx.x;

    int bx = blockIdx.x, by = blockIdx.y;
    if (EPI == 0) {
        // bijective XCD swizzle: grid (24,64), nwg=1536, 192 blocks/XCD
        const int bid = bx + by * 24;
        const int swzb = (bid & 7) * 192 + (bid >> 3);
        bx = swzb % 24;
        by = swzb / 24;
    }
    const int m0 = by * 128, n0 = bx * 128;

    const int w = t >> 6, lane = t & 63, k15 = lane & 15, g = lane >> 4;
    const int wm = (w >> 1) * 64, wn = (w & 1) * 64;
    const int srow = t >> 3, scol = (t & 7) * 8;

    f32x4 acc[4][4] = {};

    for (int k0 = 0; k0 < 1024; k0 += 64) {
        __syncthreads();
        #pragma unroll
        for (int i = 0; i < 4; ++i) {
            gload16(&A[(size_t)(m0 + i * 32 + srow) * 1024 + k0 + scol],
                    ((char*)As) + i * 4096 + t * 16);
            gload16(&B[(size_t)(n0 + i * 32 + srow) * 1024 + k0 + scol],
                    ((char*)Bs) + i * 4096 + t * 16);
        }
        __syncthreads();
        #pragma unroll
        for (int ks = 0; ks < 2; ++ks) {
            short8 af[4], bf[4];
            #pragma unroll
            for (int i = 0; i < 4; ++i) {
                af[i] = *(const short8*)&As[(wm + i * 16 + k15) * 64 + ks * 32 + g * 8];
                bf[i] = *(const short8*)&Bs[(wn + i * 16 + k15) * 64 + ks * 32 + g * 8];
            }
            #pragma unroll
            for (int mi = 0; mi < 4; ++mi)
                #pragma unroll
                for (int ni = 0; ni < 4; ++ni)
                    acc[mi][ni] = __builtin_amdgcn_mfma_f32_16x16x32_bf16(
                        af[mi], bf[ni], acc[mi][ni], 0, 0, 0);
        }
    }

    if (EPI == 0) {
        #pragma unroll
        for (int mi = 0; mi < 4; ++mi) {
            const int mbase = m0 + wm + mi * 16 + g * 4;
            const int b = mbase >> 11, s0 = mbase & 2047;
            #pragma unroll
            for (int ni = 0; ni < 4; ++ni) {
                const int e = n0 + wn + ni * 16 + k15;
                const int qi = e >> 10, h = (e >> 6) & 15, hd = e & 63;
                const int bh = b * 16 + h;
                if (qi == 2) {
                    // V transposed: [bh][d=hd][s], 4 consecutive s packed
                    const u32 lo = cvtpk(acc[mi][ni][0], acc[mi][ni][1]);
                    const u32 hi = cvtpk(acc[mi][ni][2], acc[mi][ni][3]);
                    *(uint2*)&voutb[((size_t)bh * 64 + hd) * SEQ + s0] = make_uint2(lo, hi);
                } else {
                    // fold softmax scale * log2(e) into Q (exp2-direct softmax)
                    const float scl = (qi == 0) ? 0.180336880f : 1.0f;
                    #pragma unroll
                    for (int r = 0; r < 4; ++r)
                        outb[((size_t)(qi * 64 + bh) * SEQ + s0 + r) * 64 + hd] =
                            f2bf(acc[mi][ni][r] * scl);
                }
            }
        }
    } else {
        #pragma unroll
        for (int mi = 0; mi < 4; ++mi) {
            #pragma unroll
            for (int r = 0; r < 4; ++r) {
                const size_t m = m0 + wm + mi * 16 + g * 4 + r;
                #pragma unroll
                for (int ni = 0; ni < 4; ++ni) {
                    const int e = n0 + wn + ni * 16 + k15;
                    outf[m * 1024 + e] = acc[mi][ni][r] + bias[e];
                }
            }
        }
    }
}

// ---------------------------------------------------------------------------
// Flash attention, 32x32x16 bf16 MFMA, swapped operands, DQ=2 (exact round-16
// form, proven): each wave owns TWO 32-row q-sets, 2 MFMAs per kf/vf read.
// NO-MAX-SUB softmax (exp2-direct). P in registers via cvt_pk+permlane32_swap.
// 2-phase double-buffered gload_lds staging. XCD-aware remap.
// ---------------------------------------------------------------------------
__global__ __launch_bounds__(256, 2) void attn_mfma(const ushort_t* __restrict__ qk,
                                                    const ushort_t* __restrict__ vt,
                                                    ushort_t* __restrict__ aout) {
    __shared__ __align__(16) ushort_t Ks[2][64 * 64];
    __shared__ __align__(16) ushort_t Vs[2][64 * 64];   // V^T tiles: [d][key]

    const int t = threadIdx.x, w = t >> 6, lane = t & 63;
    const int l31 = lane & 31, hi = lane >> 5;

    const int bid = blockIdx.x;
    const int j   = bid >> 3;
    const int bh  = ((bid & 7) << 3) + (j >> 3);
    const int q0  = (j & 7) * 256;

    const ushort_t* Qp = qk + (size_t)bh * SEQ * 64;
    const ushort_t* Kp = qk + (size_t)(64 + bh) * SEQ * 64;
    const ushort_t* Vp = vt + (size_t)bh * 64 * SEQ;    // [d][s]
    const int wqA = q0 + w * 64 + l31;
    const int wqB = wqA + 32;

    const int srow = t >> 3;
    const int scb8 = ((t & 7) ^ (srow & 7)) * 8;

    const ushort_t* kpA = Kp + (size_t)srow * 64 + scb8;
    const ushort_t* vpA = Vp + (size_t)srow * SEQ + scb8;

    short8 qfA[4], qfB[4];
    #pragma unroll
    for (int kc = 0; kc < 4; ++kc) {
        qfA[kc] = *(const short8*)&Qp[(size_t)wqA * 64 + kc * 16 + hi * 8];
        qfB[kc] = *(const short8*)&Qp[(size_t)wqB * 64 + kc * 16 + hi * 8];
    }

    gload16(kpA,            ((char*)Ks) + t * 16);
    gload16(kpA + 32 * 64,  ((char*)Ks) + 4096 + t * 16);
    gload16(vpA,            ((char*)Vs) + t * 16);
    gload16(vpA + 32 * SEQ, ((char*)Vs) + 4096 + t * 16);
    kpA += 64 * 64; vpA += 64;
    __syncthreads();

    f32x16 oA[2] = {}, oB[2] = {};
    float liA = 0.f, liB = 0.f;
    int cur = 0;

    for (int kt = 0; kt < SEQ / 64; ++kt) {
        if (kt + 1 < SEQ / 64) {
            char* dstK = ((char*)Ks) + (cur ^ 1) * 8192 + t * 16;
            char* dstV = ((char*)Vs) + (cur ^ 1) * 8192 + t * 16;
            gload16(kpA,            dstK);
            gload16(kpA + 32 * 64,  dstK + 4096);
            gload16(vpA,            dstV);
            gload16(vpA + 32 * SEQ, dstV + 4096);
            kpA += 64 * 64; vpA += 64;
        }

        f32x16 sA[2] = {}, sB[2] = {};
        __builtin_amdgcn_s_setprio(1);
        #pragma unroll
        for (int kt2 = 0; kt2 < 2; ++kt2) {
            #pragma unroll
            for (int kc = 0; kc < 4; ++kc) {
                const short8 kf = *(const short8*)&Ks[cur][swz8(kt2 * 32 + l31, kc * 16 + hi * 8)];
                sA[kt2] = __builtin_amdgcn_mfma_f32_32x32x16_bf16(kf, qfA[kc], sA[kt2], 0, 0, 0);
                sB[kt2] = __builtin_amdgcn_mfma_f32_32x32x16_bf16(kf, qfB[kc], sB[kt2], 0, 0, 0);
            }
        }
        __builtin_amdgcn_s_setprio(0);

        uint4 pbA[4], pbB[4];
        {
            float t0 = 0.f, t1 = 0.f, t2 = 0.f, t3 = 0.f;
            #pragma unroll
            for (int kt2 = 0; kt2 < 2; ++kt2)
                #pragma unroll
                for (int r = 0; r < 16; r += 4) {
                    const float e0 = __builtin_amdgcn_exp2f(sA[kt2][r + 0]);
                    const float e1 = __builtin_amdgcn_exp2f(sA[kt2][r + 1]);
                    const float e2 = __builtin_amdgcn_exp2f(sA[kt2][r + 2]);
                    const float e3 = __builtin_amdgcn_exp2f(sA[kt2][r + 3]);
                    sA[kt2][r + 0] = e0; sA[kt2][r + 1] = e1;
                    sA[kt2][r + 2] = e2; sA[kt2][r + 3] = e3;
                    t0 += e0; t1 += e1; t2 += e2; t3 += e3;
                }
            float rs = (t0 + t1) + (t2 + t3);
            rs += __shfl_xor(rs, 32);
            liA += rs;
            #pragma unroll
            for (int ks2 = 0; ks2 < 4; ++ks2) {
                const int r0 = (ks2 & 1) * 8;
                const int sv = ks2 >> 1;
                u32 pA = cvtpk(sA[sv][r0 + 0], sA[sv][r0 + 1]);
                u32 pB = cvtpk(sA[sv][r0 + 2], sA[sv][r0 + 3]);
                u32 pC = cvtpk(sA[sv][r0 + 4], sA[sv][r0 + 5]);
                u32 pD = cvtpk(sA[sv][r0 + 6], sA[sv][r0 + 7]);
                asm volatile("v_permlane32_swap_b32 %0, %1" : "+v"(pA), "+v"(pC));
                asm volatile("v_permlane32_swap_b32 %0, %1" : "+v"(pB), "+v"(pD));
                pbA[ks2] = make_uint4(pA, pB, pC, pD);
            }
        }
        {
            float t0 = 0.f, t1 = 0.f, t2 = 0.f, t3 = 0.f;
            #pragma unroll
            for (int kt2 = 0; kt2 < 2; ++kt2)
                #pragma unroll
                for (int r = 0; r < 16; r += 4) {
                    const float e0 = __builtin_amdgcn_exp2f(sB[kt2][r + 0]);
                    const float e1 = __builtin_amdgcn_exp2f(sB[kt2][r + 1]);
                    const float e2 = __builtin_amdgcn_exp2f(sB[kt2][r + 2]);
                    const float e3 = __builtin_amdgcn_exp2f(sB[kt2][r + 3]);
                    sB[kt2][r + 0] = e0; sB[kt2][r + 1] = e1;
                    sB[kt2][r + 2] = e2; sB[kt2][r + 3] = e3;
                    t0 += e0; t1 += e1; t2 += e2; t3 += e3;
                }
            float rs = (t0 + t1) + (t2 + t3);
            rs += __shfl_xor(rs, 32);
            liB += rs;
            #pragma unroll
            for (int ks2 = 0; ks2 < 4; ++ks2) {
                const int r0 = (ks2 & 1) * 8;
                const int sv = ks2 >> 1;
                u32 pA = cvtpk(sB[sv][r0 + 0], sB[sv][r0 + 1]);
                u32 pB = cvtpk(sB[sv][r0 + 2], sB[sv][r0 + 3]);
                u32 pC = cvtpk(sB[sv][r0 + 4], sB[sv][r0 + 5]);
                u32 pD = cvtpk(sB[sv][r0 + 6], sB[sv][r0 + 7]);
                asm volatile("v_permlane32_swap_b32 %0, %1" : "+v"(pA), "+v"(pC));
                asm volatile("v_permlane32_swap_b32 %0, %1" : "+v"(pB), "+v"(pD));
                pbB[ks2] = make_uint4(pA, pB, pC, pD);
            }
        }

        __builtin_amdgcn_s_setprio(1);
        #pragma unroll
        for (int dt = 0; dt < 2; ++dt) {
            #pragma unroll
            for (int ks2 = 0; ks2 < 4; ++ks2) {
                const short8 vf = *(const short8*)&Vs[cur][swz8(dt * 32 + l31, ks2 * 16 + hi * 8)];
                oA[dt] = __builtin_amdgcn_mfma_f32_32x32x16_bf16(
                    vf, *(const short8*)&pbA[ks2], oA[dt], 0, 0, 0);
                oB[dt] = __builtin_amdgcn_mfma_f32_32x32x16_bf16(
                    vf, *(const short8*)&pbB[ks2], oB[dt], 0, 0, 0);
            }
        }
        __builtin_amdgcn_s_setprio(0);

        __syncthreads();
        cur ^= 1;
    }

    const int b = bh >> 4, h = bh & 15;
    {
        const float inv = 1.0f / liA;
        const size_t base = ((size_t)b * SEQ + wqA) * DIM + h * 64;
        #pragma unroll
        for (int dt = 0; dt < 2; ++dt)
            #pragma unroll
            for (int rq = 0; rq < 4; ++rq) {
                const u32 lo = cvtpk(oA[dt][4 * rq + 0] * inv, oA[dt][4 * rq + 1] * inv);
                const u32 hg = cvtpk(oA[dt][4 * rq + 2] * inv, oA[dt][4 * rq + 3] * inv);
                *(uint2*)&aout[base + dt * 32 + rq * 8 + hi * 4] = make_uint2(lo, hg);
            }
    }
    {
        const float inv = 1.0f / liB;
        const size_t base = ((size_t)b * SEQ + wqB) * DIM + h * 64;
        #pragma unroll
        for (int dt = 0; dt < 2; ++dt)
            #pragma unroll
            for (int rq = 0; rq < 4; ++rq) {
                const u32 lo = cvtpk(oB[dt][4 * rq + 0] * inv, oB[dt][4 * rq + 1] * inv);
                const u32 hg = cvtpk(oB[dt][4 * rq + 2] * inv, oB[dt][4 * rq + 3] * inv);
                *(uint2*)&aout[base + dt * 32 + rq * 8 + hi * 4] = make_uint2(lo, hg);
            }
    }
}

// ---------------------------------------------------------------------------
extern "C" void kernel_launch(void* const* d_in, const int* in_sizes, int n_in,
                              void* d_out, int out_size, void* d_ws, size_t ws_size,
                              hipStream_t stream) {
    const float* x     = (const float*)d_in[0];   // [4,2048,1024]
    const float* w_qkv = (const float*)d_in[1];   // [3072,1024]
    const float* w_out = (const float*)d_in[2];   // [1024,1024]
    const float* b_out = (const float*)d_in[3];   // [1024]
    float* out = (float*)d_out;

    char* ws = (char*)d_ws;
    ushort_t* xb    = (ushort_t*)ws;                                // 16 MB
    ushort_t* wqkvb = (ushort_t*)(ws + (size_t)16 * 1024 * 1024);   // 6 MB
    ushort_t* woutb = (ushort_t*)(ws + (size_t)22 * 1024 * 1024);   // 2 MB
    ushort_t* qkb   = (ushort_t*)(ws + (size_t)24 * 1024 * 1024);   // 32 MB: [2][64][2048][64]
    ushort_t* vtb   = (ushort_t*)(ws + (size_t)56 * 1024 * 1024);   // 16 MB: [64][64][2048]
    ushort_t* aob   = (ushort_t*)(ws + (size_t)72 * 1024 * 1024);   // 16 MB: [8192][1024]

    cvt_all<<<2048, 256, 0, stream>>>(x, w_qkv, w_out, xb, wqkvb, woutb);

    gemm_bt<0><<<dim3(24, 64), 256, 0, stream>>>(xb, wqkvb, nullptr, qkb, vtb, nullptr);
    attn_mfma<<<512, 256, 0, stream>>>(qkb, vtb, aob);
    gemm_bt<1><<<dim3(8, 64), 256, 0, stream>>>(aob, woutb, b_out, nullptr, nullptr, out);
}

// Round 20
// 199.676 us; speedup vs baseline: 1.2687x; 1.0106x over previous
//
#include <hip/hip_runtime.h>

#define DIM 1024
#define SEQ 2048

typedef unsigned short ushort_t;
typedef unsigned int u32;
typedef __attribute__((ext_vector_type(8))) short short8;
typedef __attribute__((ext_vector_type(8))) unsigned short ushort8;
typedef __attribute__((ext_vector_type(4))) float f32x4;
typedef __attribute__((ext_vector_type(16))) float f32x16;

__device__ __forceinline__ ushort_t f2bf(float x) {
    u32 u = __float_as_uint(x);
    u32 r = (u + 0x7fffu + ((u >> 16) & 1u)) >> 16;
    return (ushort_t)r;
}

__device__ __forceinline__ u32 cvtpk(float lo, float hi) {
    u32 r;
    asm("v_cvt_pk_bf16_f32 %0, %1, %2" : "=v"(r) : "v"(lo), "v"(hi));
    return r;
}

__device__ __forceinline__ void gload16(const void* g, void* l) {
    __builtin_amdgcn_global_load_lds(
        (const __attribute__((address_space(1))) u32*)g,
        (__attribute__((address_space(3))) u32*)l, 16, 0, 0);
}

// XOR-swizzled element index within a [rows][64-bf16] tile (8-elem groups)
__device__ __forceinline__ int swz8(int row, int col) {
    return row * 64 + ((((col >> 3) ^ (row & 7)) << 3) | (col & 7));
}

// ---------------------------------------------------------------------------
// fused fp32 -> bf16 conversion of all three inputs (one dispatch)
// ---------------------------------------------------------------------------
__global__ __launch_bounds__(256) void cvt_all(const float* __restrict__ x,
                                               const float* __restrict__ wq,
                                               const float* __restrict__ wo,
                                               ushort_t* __restrict__ xb,
                                               ushort_t* __restrict__ wqb,
                                               ushort_t* __restrict__ wob) {
    for (int i = blockIdx.x * blockDim.x + threadIdx.x; i < 1572864;
         i += gridDim.x * blockDim.x) {
        const float* in; ushort_t* out; int off;
        if (i < 1048576)      { in = x;  out = xb;  off = i; }
        else if (i < 1441792) { in = wq; out = wqb; off = i - 1048576; }
        else                  { in = wo; out = wob; off = i - 1441792; }
        const float4 a = ((const float4*)in)[2 * off];
        const float4 b = ((const float4*)in)[2 * off + 1];
        ushort8 o;
        o[0] = f2bf(a.x); o[1] = f2bf(a.y); o[2] = f2bf(a.z); o[3] = f2bf(a.w);
        o[4] = f2bf(b.x); o[5] = f2bf(b.y); o[6] = f2bf(b.z); o[7] = f2bf(b.w);
        ((ushort8*)out)[off] = o;
    }
}

// ---------------------------------------------------------------------------
// bf16 GEMM, m97 structure, 128x128 tile — EXACT round-16 proven form.
// (r18: min-waves cap below the ~104-VGPR live range -> catastrophic spill.
//  r19: XCD swizzle on this 1.5-generation grid RAISES fetch (77->84 MB) —
//  sharers land in different generations; swizzle removed.)
// EPI 0: Q (pre-scaled 0.125*log2e) and K -> [2][bh][s][64];
//        V -> TRANSPOSED buffer [bh][d=64][s=2048] (uint2-packed stores)
// EPI 1: fp32 out + bias
// ---------------------------------------------------------------------------
template <int EPI>
__global__ __launch_bounds__(256) void gemm_bt(const ushort_t* __restrict__ A,
                                               const ushort_t* __restrict__ B,
                                               const float* __restrict__ bias,
                                               ushort_t* __restrict__ outb,
                                               ushort_t* __restrict__ voutb,
                                               float* __restrict__ outf) {
    __shared__ __align__(16) ushort_t As[128 * 64];
    __shared__ __align__(16) ushort_t Bs[128 * 64];
    const int t = threadIdx.x;
    const int m0 = blockIdx.y * 128, n0 = blockIdx.x * 128;
    const int w = t >> 6, lane = t & 63, k15 = lane & 15, g = lane >> 4;
    const int wm = (w >> 1) * 64, wn = (w & 1) * 64;
    const int srow = t >> 3, scol = (t & 7) * 8;

    f32x4 acc[4][4] = {};

    for (int k0 = 0; k0 < 1024; k0 += 64) {
        __syncthreads();
        #pragma unroll
        for (int i = 0; i < 4; ++i) {
            gload16(&A[(size_t)(m0 + i * 32 + srow) * 1024 + k0 + scol],
                    ((char*)As) + i * 4096 + t * 16);
            gload16(&B[(size_t)(n0 + i * 32 + srow) * 1024 + k0 + scol],
                    ((char*)Bs) + i * 4096 + t * 16);
        }
        __syncthreads();
        #pragma unroll
        for (int ks = 0; ks < 2; ++ks) {
            short8 af[4], bf[4];
            #pragma unroll
            for (int i = 0; i < 4; ++i) {
                af[i] = *(const short8*)&As[(wm + i * 16 + k15) * 64 + ks * 32 + g * 8];
                bf[i] = *(const short8*)&Bs[(wn + i * 16 + k15) * 64 + ks * 32 + g * 8];
            }
            #pragma unroll
            for (int mi = 0; mi < 4; ++mi)
                #pragma unroll
                for (int ni = 0; ni < 4; ++ni)
                    acc[mi][ni] = __builtin_amdgcn_mfma_f32_16x16x32_bf16(
                        af[mi], bf[ni], acc[mi][ni], 0, 0, 0);
        }
    }

    if (EPI == 0) {
        #pragma unroll
        for (int mi = 0; mi < 4; ++mi) {
            const int mbase = m0 + wm + mi * 16 + g * 4;
            const int b = mbase >> 11, s0 = mbase & 2047;
            #pragma unroll
            for (int ni = 0; ni < 4; ++ni) {
                const int e = n0 + wn + ni * 16 + k15;
                const int qi = e >> 10, h = (e >> 6) & 15, hd = e & 63;
                const int bh = b * 16 + h;
                if (qi == 2) {
                    // V transposed: [bh][d=hd][s], 4 consecutive s packed
                    const u32 lo = cvtpk(acc[mi][ni][0], acc[mi][ni][1]);
                    const u32 hi = cvtpk(acc[mi][ni][2], acc[mi][ni][3]);
                    *(uint2*)&voutb[((size_t)bh * 64 + hd) * SEQ + s0] = make_uint2(lo, hi);
                } else {
                    // fold softmax scale * log2(e) into Q (exp2-direct softmax)
                    const float scl = (qi == 0) ? 0.180336880f : 1.0f;
                    #pragma unroll
                    for (int r = 0; r < 4; ++r)
                        outb[((size_t)(qi * 64 + bh) * SEQ + s0 + r) * 64 + hd] =
                            f2bf(acc[mi][ni][r] * scl);
                }
            }
        }
    } else {
        #pragma unroll
        for (int mi = 0; mi < 4; ++mi) {
            #pragma unroll
            for (int r = 0; r < 4; ++r) {
                const size_t m = m0 + wm + mi * 16 + g * 4 + r;
                #pragma unroll
                for (int ni = 0; ni < 4; ++ni) {
                    const int e = n0 + wn + ni * 16 + k15;
                    outf[m * 1024 + e] = acc[mi][ni][r] + bias[e];
                }
            }
        }
    }
}

// ---------------------------------------------------------------------------
// Flash attention, 32x32x16 bf16 MFMA, swapped operands, DQ=2 (exact round-16
// form, proven): each wave owns TWO 32-row q-sets, 2 MFMAs per kf/vf read.
// NO-MAX-SUB softmax (exp2-direct). P in registers via cvt_pk+permlane32_swap.
// 2-phase double-buffered gload_lds staging. XCD-aware remap.
// ---------------------------------------------------------------------------
__global__ __launch_bounds__(256, 2) void attn_mfma(const ushort_t* __restrict__ qk,
                                                    const ushort_t* __restrict__ vt,
                                                    ushort_t* __restrict__ aout) {
    __shared__ __align__(16) ushort_t Ks[2][64 * 64];
    __shared__ __align__(16) ushort_t Vs[2][64 * 64];   // V^T tiles: [d][key]

    const int t = threadIdx.x, w = t >> 6, lane = t & 63;
    const int l31 = lane & 31, hi = lane >> 5;

    const int bid = blockIdx.x;
    const int j   = bid >> 3;
    const int bh  = ((bid & 7) << 3) + (j >> 3);
    const int q0  = (j & 7) * 256;

    const ushort_t* Qp = qk + (size_t)bh * SEQ * 64;
    const ushort_t* Kp = qk + (size_t)(64 + bh) * SEQ * 64;
    const ushort_t* Vp = vt + (size_t)bh * 64 * SEQ;    // [d][s]
    const int wqA = q0 + w * 64 + l31;
    const int wqB = wqA + 32;

    const int srow = t >> 3;
    const int scb8 = ((t & 7) ^ (srow & 7)) * 8;

    const ushort_t* kpA = Kp + (size_t)srow * 64 + scb8;
    const ushort_t* vpA = Vp + (size_t)srow * SEQ + scb8;

    short8 qfA[4], qfB[4];
    #pragma unroll
    for (int kc = 0; kc < 4; ++kc) {
        qfA[kc] = *(const short8*)&Qp[(size_t)wqA * 64 + kc * 16 + hi * 8];
        qfB[kc] = *(const short8*)&Qp[(size_t)wqB * 64 + kc * 16 + hi * 8];
    }

    gload16(kpA,            ((char*)Ks) + t * 16);
    gload16(kpA + 32 * 64,  ((char*)Ks) + 4096 + t * 16);
    gload16(vpA,            ((char*)Vs) + t * 16);
    gload16(vpA + 32 * SEQ, ((char*)Vs) + 4096 + t * 16);
    kpA += 64 * 64; vpA += 64;
    __syncthreads();

    f32x16 oA[2] = {}, oB[2] = {};
    float liA = 0.f, liB = 0.f;
    int cur = 0;

    for (int kt = 0; kt < SEQ / 64; ++kt) {
        if (kt + 1 < SEQ / 64) {
            char* dstK = ((char*)Ks) + (cur ^ 1) * 8192 + t * 16;
            char* dstV = ((char*)Vs) + (cur ^ 1) * 8192 + t * 16;
            gload16(kpA,            dstK);
            gload16(kpA + 32 * 64,  dstK + 4096);
            gload16(vpA,            dstV);
            gload16(vpA + 32 * SEQ, dstV + 4096);
            kpA += 64 * 64; vpA += 64;
        }

        f32x16 sA[2] = {}, sB[2] = {};
        __builtin_amdgcn_s_setprio(1);
        #pragma unroll
        for (int kt2 = 0; kt2 < 2; ++kt2) {
            #pragma unroll
            for (int kc = 0; kc < 4; ++kc) {
                const short8 kf = *(const short8*)&Ks[cur][swz8(kt2 * 32 + l31, kc * 16 + hi * 8)];
                sA[kt2] = __builtin_amdgcn_mfma_f32_32x32x16_bf16(kf, qfA[kc], sA[kt2], 0, 0, 0);
                sB[kt2] = __builtin_amdgcn_mfma_f32_32x32x16_bf16(kf, qfB[kc], sB[kt2], 0, 0, 0);
            }
        }
        __builtin_amdgcn_s_setprio(0);

        uint4 pbA[4], pbB[4];
        {
            float t0 = 0.f, t1 = 0.f, t2 = 0.f, t3 = 0.f;
            #pragma unroll
            for (int kt2 = 0; kt2 < 2; ++kt2)
                #pragma unroll
                for (int r = 0; r < 16; r += 4) {
                    const float e0 = __builtin_amdgcn_exp2f(sA[kt2][r + 0]);
                    const float e1 = __builtin_amdgcn_exp2f(sA[kt2][r + 1]);
                    const float e2 = __builtin_amdgcn_exp2f(sA[kt2][r + 2]);
                    const float e3 = __builtin_amdgcn_exp2f(sA[kt2][r + 3]);
                    sA[kt2][r + 0] = e0; sA[kt2][r + 1] = e1;
                    sA[kt2][r + 2] = e2; sA[kt2][r + 3] = e3;
                    t0 += e0; t1 += e1; t2 += e2; t3 += e3;
                }
            float rs = (t0 + t1) + (t2 + t3);
            rs += __shfl_xor(rs, 32);
            liA += rs;
            #pragma unroll
            for (int ks2 = 0; ks2 < 4; ++ks2) {
                const int r0 = (ks2 & 1) * 8;
                const int sv = ks2 >> 1;
                u32 pA = cvtpk(sA[sv][r0 + 0], sA[sv][r0 + 1]);
                u32 pB = cvtpk(sA[sv][r0 + 2], sA[sv][r0 + 3]);
                u32 pC = cvtpk(sA[sv][r0 + 4], sA[sv][r0 + 5]);
                u32 pD = cvtpk(sA[sv][r0 + 6], sA[sv][r0 + 7]);
                asm volatile("v_permlane32_swap_b32 %0, %1" : "+v"(pA), "+v"(pC));
                asm volatile("v_permlane32_swap_b32 %0, %1" : "+v"(pB), "+v"(pD));
                pbA[ks2] = make_uint4(pA, pB, pC, pD);
            }
        }
        {
            float t0 = 0.f, t1 = 0.f, t2 = 0.f, t3 = 0.f;
            #pragma unroll
            for (int kt2 = 0; kt2 < 2; ++kt2)
                #pragma unroll
                for (int r = 0; r < 16; r += 4) {
                    const float e0 = __builtin_amdgcn_exp2f(sB[kt2][r + 0]);
                    const float e1 = __builtin_amdgcn_exp2f(sB[kt2][r + 1]);
                    const float e2 = __builtin_amdgcn_exp2f(sB[kt2][r + 2]);
                    const float e3 = __builtin_amdgcn_exp2f(sB[kt2][r + 3]);
                    sB[kt2][r + 0] = e0; sB[kt2][r + 1] = e1;
                    sB[kt2][r + 2] = e2; sB[kt2][r + 3] = e3;
                    t0 += e0; t1 += e1; t2 += e2; t3 += e3;
                }
            float rs = (t0 + t1) + (t2 + t3);
            rs += __shfl_xor(rs, 32);
            liB += rs;
            #pragma unroll
            for (int ks2 = 0; ks2 < 4; ++ks2) {
                const int r0 = (ks2 & 1) * 8;
                const int sv = ks2 >> 1;
                u32 pA = cvtpk(sB[sv][r0 + 0], sB[sv][r0 + 1]);
                u32 pB = cvtpk(sB[sv][r0 + 2], sB[sv][r0 + 3]);
                u32 pC = cvtpk(sB[sv][r0 + 4], sB[sv][r0 + 5]);
                u32 pD = cvtpk(sB[sv][r0 + 6], sB[sv][r0 + 7]);
                asm volatile("v_permlane32_swap_b32 %0, %1" : "+v"(pA), "+v"(pC));
                asm volatile("v_permlane32_swap_b32 %0, %1" : "+v"(pB), "+v"(pD));
                pbB[ks2] = make_uint4(pA, pB, pC, pD);
            }
        }

        __builtin_amdgcn_s_setprio(1);
        #pragma unroll
        for (int dt = 0; dt < 2; ++dt) {
            #pragma unroll
            for (int ks2 = 0; ks2 < 4; ++ks2) {
                const short8 vf = *(const short8*)&Vs[cur][swz8(dt * 32 + l31, ks2 * 16 + hi * 8)];
                oA[dt] = __builtin_amdgcn_mfma_f32_32x32x16_bf16(
                    vf, *(const short8*)&pbA[ks2], oA[dt], 0, 0, 0);
                oB[dt] = __builtin_amdgcn_mfma_f32_32x32x16_bf16(
                    vf, *(const short8*)&pbB[ks2], oB[dt], 0, 0, 0);
            }
        }
        __builtin_amdgcn_s_setprio(0);

        __syncthreads();
        cur ^= 1;
    }

    const int b = bh >> 4, h = bh & 15;
    {
        const float inv = 1.0f / liA;
        const size_t base = ((size_t)b * SEQ + wqA) * DIM + h * 64;
        #pragma unroll
        for (int dt = 0; dt < 2; ++dt)
            #pragma unroll
            for (int rq = 0; rq < 4; ++rq) {
                const u32 lo = cvtpk(oA[dt][4 * rq + 0] * inv, oA[dt][4 * rq + 1] * inv);
                const u32 hg = cvtpk(oA[dt][4 * rq + 2] * inv, oA[dt][4 * rq + 3] * inv);
                *(uint2*)&aout[base + dt * 32 + rq * 8 + hi * 4] = make_uint2(lo, hg);
            }
    }
    {
        const float inv = 1.0f / liB;
        const size_t base = ((size_t)b * SEQ + wqB) * DIM + h * 64;
        #pragma unroll
        for (int dt = 0; dt < 2; ++dt)
            #pragma unroll
            for (int rq = 0; rq < 4; ++rq) {
                const u32 lo = cvtpk(oB[dt][4 * rq + 0] * inv, oB[dt][4 * rq + 1] * inv);
                const u32 hg = cvtpk(oB[dt][4 * rq + 2] * inv, oB[dt][4 * rq + 3] * inv);
                *(uint2*)&aout[base + dt * 32 + rq * 8 + hi * 4] = make_uint2(lo, hg);
            }
    }
}

// ---------------------------------------------------------------------------
extern "C" void kernel_launch(void* const* d_in, const int* in_sizes, int n_in,
                              void* d_out, int out_size, void* d_ws, size_t ws_size,
                              hipStream_t stream) {
    const float* x     = (const float*)d_in[0];   // [4,2048,1024]
    const float* w_qkv = (const float*)d_in[1];   // [3072,1024]
    const float* w_out = (const float*)d_in[2];   // [1024,1024]
    const float* b_out = (const float*)d_in[3];   // [1024]
    float* out = (float*)d_out;

    char* ws = (char*)d_ws;
    ushort_t* xb    = (ushort_t*)ws;                                // 16 MB
    ushort_t* wqkvb = (ushort_t*)(ws + (size_t)16 * 1024 * 1024);   // 6 MB
    ushort_t* woutb = (ushort_t*)(ws + (size_t)22 * 1024 * 1024);   // 2 MB
    ushort_t* qkb   = (ushort_t*)(ws + (size_t)24 * 1024 * 1024);   // 32 MB: [2][64][2048][64]
    ushort_t* vtb   = (ushort_t*)(ws + (size_t)56 * 1024 * 1024);   // 16 MB: [64][64][2048]
    ushort_t* aob   = (ushort_t*)(ws + (size_t)72 * 1024 * 1024);   // 16 MB: [8192][1024]

    cvt_all<<<2048, 256, 0, stream>>>(x, w_qkv, w_out, xb, wqkvb, woutb);

    gemm_bt<0><<<dim3(24, 64), 256, 0, stream>>>(xb, wqkvb, nullptr, qkb, vtb, nullptr);
    attn_mfma<<<512, 256, 0, stream>>>(qkb, vtb, aob);
    gemm_bt<1><<<dim3(8, 64), 256, 0, stream>>>(aob, woutb, b_out, nullptr, nullptr, out);
}